// Round 7
// baseline (337.906 us; speedup 1.0000x reference)
//
#include <hip/hip_runtime.h>
#include <math.h>

#define N_NODES 50000
#define N_EDGES 800000
#define NFEAT 256
#define HID 64
#define NCLS 40
#define EPS_RES 0.3f
#define ROWSZ 68  // LDS row pitch for proj (64 + 4 pad)
#define SCAN_BLOCKS ((N_NODES + 255) / 256)  // 196
#define NXCD 8

typedef unsigned int uint;
typedef unsigned short ushort;

__device__ __forceinline__ float bflo(uint u) { return __uint_as_float(u << 16); }
__device__ __forceinline__ float bfhi(uint u) { return __uint_as_float(u & 0xFFFF0000u); }
__device__ __forceinline__ uint bf16rne(float f) {
    uint u = __float_as_uint(f);
    return (u + 0x7FFFu + ((u >> 16) & 1u)) >> 16;
}
__device__ __forceinline__ uint bf16rne2(float a, float b) {
    return bf16rne(a) | (bf16rne(b) << 16);
}

__device__ __forceinline__ uint xcc_id() {
    uint x;
    asm volatile("s_getreg_b32 %0, hwreg(HW_REG_XCC_ID)" : "=s"(x));
    return x & 7;
}

// ---------------- degree histograms: XCD-private replicas, workgroup-scope atomics ------
// Device-scope atomics cost a ~32B fabric write-through each (~19 ops/ns ceiling, measured
// R1/R5). Workgroup-scope atomics into an XCD-private replica resolve in the local L2.
__global__ void degree_kernel(const int* __restrict__ row, const int* __restrict__ col,
                              int* __restrict__ histD, int* __restrict__ histC,
                              int* __restrict__ rankx) {
    int e = blockIdx.x * 256 + threadIdx.x;
    uint xcc = xcc_id();
    int* hd = histD + xcc * N_NODES;
    int* hc = histC + xcc * N_NODES;
    __hip_atomic_fetch_add(&hd[row[e]], 1, __ATOMIC_RELAXED, __HIP_MEMORY_SCOPE_WORKGROUP);
    int rk = __hip_atomic_fetch_add(&hc[col[e]], 1, __ATOMIC_RELAXED, __HIP_MEMORY_SCOPE_WORKGROUP);
    rankx[e] = (rk << 3) | (int)xcc;
}

// ---------------- reduce replicas: totals + in-place exclusive base per replica ---------
__global__ void reduce_kernel(const int* __restrict__ histD, int* __restrict__ histC,
                              int* __restrict__ degT, int* __restrict__ cntT) {
    int n = blockIdx.x * 256 + threadIdx.x;
    if (n >= N_NODES) return;
    int sD = 0;
#pragma unroll
    for (int r = 0; r < NXCD; r++) sD += histD[r * N_NODES + n];
    degT[n] = sD;
    int run = 0;
#pragma unroll
    for (int r = 0; r < NXCD; r++) {
        int v = histC[r * N_NODES + n];
        histC[r * N_NODES + n] = run;  // becomes per-replica base within this col's bucket
        run += v;
    }
    cntT[n] = run;
}

// ---------------- 3-phase grid-wide exclusive scan of cntT -> off (+ fused nd/invcnt) ----
__device__ __forceinline__ int block_excl_scan_256(int v, int t, int* wsum) {
    int lane = t & 63, w = t >> 6;
    int sv = v;
#pragma unroll
    for (int d = 1; d < 64; d <<= 1) {
        int o = __shfl_up(sv, d);
        if (lane >= d) sv += o;
    }
    if (lane == 63) wsum[w] = sv;
    __syncthreads();
    int add = 0;
    for (int i = 0; i < w; i++) add += wsum[i];
    return sv + add - v;
}

__global__ void scan1_kernel(const int* __restrict__ cntT, const int* __restrict__ degT,
                             int* __restrict__ off, int* __restrict__ bsum,
                             float* __restrict__ nd, float* __restrict__ invcnt) {
    __shared__ int wsum[4];
    int t = threadIdx.x;
    int idx = blockIdx.x * 256 + t;
    int v = (idx < N_NODES) ? cntT[idx] : 0;
    if (idx < N_NODES) {
        int d = degT[idx]; if (d < 1) d = 1;
        nd[idx] = rsqrtf((float)d);
        int c = v; if (c < 1) c = 1;
        invcnt[idx] = 1.0f / (float)c;
    }
    int excl = block_excl_scan_256(v, t, wsum);
    if (idx < N_NODES) off[idx] = excl;
    if (t == 255) bsum[blockIdx.x] = excl + v;
}

__global__ void scan2_kernel(int* __restrict__ bsum) {
    __shared__ int wsum[4];
    int t = threadIdx.x;
    int v = (t < SCAN_BLOCKS) ? bsum[t] : 0;
    int excl = block_excl_scan_256(v, t, wsum);
    if (t < SCAN_BLOCKS) bsum[t] = excl;
}

__global__ void scan3_kernel(int* __restrict__ off, const int* __restrict__ bsum) {
    int t = threadIdx.x;
    int idx = blockIdx.x * 256 + t;
    if (idx < N_NODES) off[idx] += bsum[blockIdx.x];
    if (idx == 0) off[N_NODES] = N_EDGES;
}

// ---------------- CSR scatter: atomic-free, one 8B store per edge ----------------
__global__ void scatter_kernel(const int* __restrict__ row, const int* __restrict__ col,
                               const int* __restrict__ rankx, const int* __restrict__ baseC,
                               const int* __restrict__ off, const float* __restrict__ nd,
                               int2* __restrict__ sedge) {
    int e = blockIdx.x * 256 + threadIdx.x;
    int r = row[e], c = col[e];
    int rx = rankx[e];
    int xcc = rx & 7, rk = rx >> 3;
    int p = off[c] + baseC[xcc * N_NODES + c] + rk;
    int2 se;
    se.x = r;
    se.y = __float_as_int(nd[r] * nd[c]);
    sedge[p] = se;
}

// ---------------- input projection: ha(fp32) + habf(bf16) = relu(x @ W1^T + b1) ----------
__global__ __launch_bounds__(256) void proj_kernel(const float* __restrict__ x,
                                                   const float* __restrict__ W1,
                                                   const float* __restrict__ b1,
                                                   float* __restrict__ ha,
                                                   ushort* __restrict__ habf) {
    __shared__ float xs[64 * ROWSZ];
    __shared__ float ws[64 * ROWSZ];
    int t = threadIdx.x;
    int nb = blockIdx.x * 64;
    int lane = t & 63, w = t >> 6;
    int l15 = lane & 15, g = lane >> 4;
    int hbase = 16 * w + 4 * g;
    float acc[4][4];
#pragma unroll
    for (int j = 0; j < 4; j++)
#pragma unroll
        for (int i = 0; i < 4; i++) acc[j][i] = 0.f;

    for (int kc = 0; kc < NFEAT; kc += 64) {
        __syncthreads();
#pragma unroll
        for (int i = 0; i < 4; i++) {
            int idx = t + 256 * i;
            int r_ = idx >> 4;
            int kq = idx & 15;
            int gn = nb + r_;
            float4 v = make_float4(0.f, 0.f, 0.f, 0.f);
            if (gn < N_NODES) v = *(const float4*)(x + (size_t)gn * NFEAT + kc + kq * 4);
            *(float4*)(xs + r_ * ROWSZ + kq * 4) = v;
            float4 wv = *(const float4*)(W1 + (size_t)r_ * NFEAT + kc + kq * 4);
            *(float4*)(ws + r_ * ROWSZ + kq * 4) = wv;
        }
        __syncthreads();
#pragma unroll 4
        for (int k = 0; k < 64; k += 4) {
            float4 a[4], b[4];
#pragma unroll
            for (int j = 0; j < 4; j++) a[j] = *(const float4*)(xs + (l15 + 16 * j) * ROWSZ + k);
#pragma unroll
            for (int i = 0; i < 4; i++) b[i] = *(const float4*)(ws + (hbase + i) * ROWSZ + k);
#pragma unroll
            for (int j = 0; j < 4; j++)
#pragma unroll
                for (int i = 0; i < 4; i++)
                    acc[j][i] += a[j].x * b[i].x + a[j].y * b[i].y + a[j].z * b[i].z + a[j].w * b[i].w;
        }
    }
    float4 bias = *(const float4*)(b1 + hbase);
#pragma unroll
    for (int j = 0; j < 4; j++) {
        int gn = nb + l15 + 16 * j;
        if (gn < N_NODES) {
            float4 o;
            o.x = fmaxf(acc[j][0] + bias.x, 0.f);
            o.y = fmaxf(acc[j][1] + bias.y, 0.f);
            o.z = fmaxf(acc[j][2] + bias.z, 0.f);
            o.w = fmaxf(acc[j][3] + bias.w, 0.f);
            *(float4*)(ha + (size_t)gn * HID + hbase) = o;
            uint2 pk;
            pk.x = bf16rne2(o.x, o.y);
            pk.y = bf16rne2(o.z, o.w);
            *(uint2*)(habf + (size_t)gn * HID + hbase) = pk;
        }
    }
}

// ---------------- per-node gate projections: y = h.wa, z = h.wb ----------------
__global__ void yz_kernel(const float* __restrict__ h, const float* __restrict__ gw,
                          float* __restrict__ y, float* __restrict__ z) {
    int t = threadIdx.x;
    int lane = t & 63;
    int node = blockIdx.x * 4 + (t >> 6);
    float wa = gw[lane], wb = gw[HID + lane];
    float v = h[node * HID + lane];
    float p = v * wa, q = v * wb;
#pragma unroll
    for (int s = 1; s < 64; s <<= 1) { p += __shfl_xor(p, s); q += __shfl_xor(q, s); }
    if (lane == 0) { y[node] = p; z[node] = q; }
}

// ---------------- CSR aggregation core: 8 edges/iter, bf16 gathers, fused gate ----------
__device__ __forceinline__ void agg_core8(const ushort* __restrict__ hbf,
                                          const int2* __restrict__ sedge,
                                          const float* __restrict__ y,
                                          float zc_b, int e0, int e1, int q, int c8,
                                          float acc[8], float& gs_out) {
#pragma unroll
    for (int i = 0; i < 8; i++) acc[i] = 0.f;
    float gs = 0.f;
    if (e0 < e1) {
        int e = e0 + q;
        int ec = (e < e1) ? e : e0;
        int2 se = sedge[ec];
        int r_n = se.x;
        float nde_n = (e < e1) ? __int_as_float(se.y) : 0.f;
        float y_n = y[r_n];
        uint4 u_n = *(const uint4*)(hbf + (size_t)r_n * HID + c8);
        for (int base = e0; base < e1; base += 8) {
            int e2 = base + 8 + q;
            int ec2 = (e2 < e1) ? e2 : e0;
            int2 se2 = sedge[ec2];
            float nde2 = (e2 < e1) ? __int_as_float(se2.y) : 0.f;
            float y2v = y[se2.x];
            uint4 u2 = *(const uint4*)(hbf + (size_t)se2.x * HID + c8);
            float g = tanhf(y_n + zc_b) * nde_n;
            acc[0] += g * bflo(u_n.x);
            acc[1] += g * bfhi(u_n.x);
            acc[2] += g * bflo(u_n.y);
            acc[3] += g * bfhi(u_n.y);
            acc[4] += g * bflo(u_n.z);
            acc[5] += g * bfhi(u_n.z);
            acc[6] += g * bflo(u_n.w);
            acc[7] += g * bfhi(u_n.w);
            gs += g;
            nde_n = nde2; y_n = y2v; u_n = u2;
        }
    }
#pragma unroll
    for (int s = 8; s < 64; s <<= 1) {
#pragma unroll
        for (int i = 0; i < 8; i++) acc[i] += __shfl_xor(acc[i], s);
        gs += __shfl_xor(gs, s);
    }
    gs_out = gs;
}

// ---------------- layer 1 agg + fused y2/z2; writes bf16 hbbf only ----------------
__global__ void agg1_kernel(const float* __restrict__ ha, const ushort* __restrict__ habf,
                            const int2* __restrict__ sedge, const int* __restrict__ off,
                            const float* __restrict__ invcnt, const float* __restrict__ y,
                            const float* __restrict__ z, const float* __restrict__ gb,
                            const float* __restrict__ gw2, ushort* __restrict__ hbbf,
                            float* __restrict__ y2, float* __restrict__ z2) {
    int t = threadIdx.x;
    int lane = t & 63;
    int node = blockIdx.x * 4 + (t >> 6);
    int q = lane >> 3, c8 = (lane & 7) * 8;
    float4 ra = *(const float4*)(ha + (size_t)node * HID + c8);
    float4 rb = *(const float4*)(ha + (size_t)node * HID + c8 + 4);
    float raw8[8] = {ra.x, ra.y, ra.z, ra.w, rb.x, rb.y, rb.z, rb.w};
    float zc_b = z[node] + gb[0];
    float acc[8]; float gs;
    agg_core8(habf, sedge, y, zc_b, off[node], off[node + 1], q, c8, acc, gs);
    float invc = invcnt[node];
    float o[8];
#pragma unroll
    for (int i = 0; i < 8; i++) o[i] = EPS_RES * raw8[i] + (acc[i] + gs * raw8[i]) * invc;
    if (q == 0) {
        uint4 pk;
        pk.x = bf16rne2(o[0], o[1]);
        pk.y = bf16rne2(o[2], o[3]);
        pk.z = bf16rne2(o[4], o[5]);
        pk.w = bf16rne2(o[6], o[7]);
        *(uint4*)(hbbf + (size_t)node * HID + c8) = pk;
    }
    float4 wa0 = *(const float4*)(gw2 + c8);
    float4 wa1 = *(const float4*)(gw2 + c8 + 4);
    float4 wb0 = *(const float4*)(gw2 + HID + c8);
    float4 wb1 = *(const float4*)(gw2 + HID + c8 + 4);
    float p = o[0] * wa0.x + o[1] * wa0.y + o[2] * wa0.z + o[3] * wa0.w
            + o[4] * wa1.x + o[5] * wa1.y + o[6] * wa1.z + o[7] * wa1.w;
    float qq = o[0] * wb0.x + o[1] * wb0.y + o[2] * wb0.z + o[3] * wb0.w
             + o[4] * wb1.x + o[5] * wb1.y + o[6] * wb1.z + o[7] * wb1.w;
#pragma unroll
    for (int s = 1; s < 8; s <<= 1) { p += __shfl_xor(p, s); qq += __shfl_xor(qq, s); }
    if (lane == 0) { y2[node] = p; z2[node] = qq; }
}

// ---------------- layer 2 agg + classifier + log_softmax ----------------
__global__ void agg2_kernel(const ushort* __restrict__ hbbf, const float* __restrict__ ha,
                            const int2* __restrict__ sedge, const int* __restrict__ off,
                            const float* __restrict__ invcnt, const float* __restrict__ y2,
                            const float* __restrict__ z2, const float* __restrict__ gb,
                            const float* __restrict__ W2, const float* __restrict__ b2,
                            float* __restrict__ out) {
    __shared__ float w2s[NCLS * 65];
    __shared__ float b2s[NCLS];
    __shared__ float hs[4 * HID];
    int t = threadIdx.x;
    for (int i = t; i < NCLS * HID; i += 256) w2s[(i >> 6) * 65 + (i & 63)] = W2[i];
    if (t < NCLS) b2s[t] = b2[t];
    int lane = t & 63;
    int wv = t >> 6;
    int node = blockIdx.x * 4 + wv;
    int q = lane >> 3, c8 = (lane & 7) * 8;
    uint4 hc = *(const uint4*)(hbbf + (size_t)node * HID + c8);
    float hcv[8] = {bflo(hc.x), bfhi(hc.x), bflo(hc.y), bfhi(hc.y),
                    bflo(hc.z), bfhi(hc.z), bflo(hc.w), bfhi(hc.w)};
    float4 ra = *(const float4*)(ha + (size_t)node * HID + c8);
    float4 rb = *(const float4*)(ha + (size_t)node * HID + c8 + 4);
    float raw8[8] = {ra.x, ra.y, ra.z, ra.w, rb.x, rb.y, rb.z, rb.w};
    float zc_b = z2[node] + gb[0];
    float acc[8]; float gs;
    agg_core8(hbbf, sedge, y2, zc_b, off[node], off[node + 1], q, c8, acc, gs);
    float invc = invcnt[node];
    if (q == 0) {
        float4 o0, o1;
        o0.x = EPS_RES * raw8[0] + (acc[0] + gs * hcv[0]) * invc;
        o0.y = EPS_RES * raw8[1] + (acc[1] + gs * hcv[1]) * invc;
        o0.z = EPS_RES * raw8[2] + (acc[2] + gs * hcv[2]) * invc;
        o0.w = EPS_RES * raw8[3] + (acc[3] + gs * hcv[3]) * invc;
        o1.x = EPS_RES * raw8[4] + (acc[4] + gs * hcv[4]) * invc;
        o1.y = EPS_RES * raw8[5] + (acc[5] + gs * hcv[5]) * invc;
        o1.z = EPS_RES * raw8[6] + (acc[6] + gs * hcv[6]) * invc;
        o1.w = EPS_RES * raw8[7] + (acc[7] + gs * hcv[7]) * invc;
        *(float4*)(hs + wv * HID + c8) = o0;
        *(float4*)(hs + wv * HID + c8 + 4) = o1;
    }
    __syncthreads();
    float logit = 0.f;
    if (lane < NCLS) {
        const float* wr = w2s + lane * 65;
        const float* hrow = hs + wv * HID;
#pragma unroll
        for (int k = 0; k < HID; k++) logit += hrow[k] * wr[k];
        logit += b2s[lane];
    }
    float v = (lane < NCLS) ? logit : -INFINITY;
#pragma unroll
    for (int s = 1; s < 64; s <<= 1) v = fmaxf(v, __shfl_xor(v, s));
    float ex = (lane < NCLS) ? expf(logit - v) : 0.f;
#pragma unroll
    for (int s = 1; s < 64; s <<= 1) ex += __shfl_xor(ex, s);
    float ls = v + logf(ex);
    if (lane < NCLS) out[node * NCLS + lane] = logit - ls;
}

extern "C" void kernel_launch(void* const* d_in, const int* in_sizes, int n_in,
                              void* d_out, int out_size, void* d_ws, size_t ws_size,
                              hipStream_t stream) {
    const float* x  = (const float*)d_in[0];
    const int*   ei = (const int*)d_in[1];
    const float* W1 = (const float*)d_in[2];
    const float* b1 = (const float*)d_in[3];
    const float* W2 = (const float*)d_in[4];
    const float* b2 = (const float*)d_in[5];
    const float* gw = (const float*)d_in[6];
    const float* gb = (const float*)d_in[7];
    float* out = (float*)d_out;

    // ws layout (4B words): [degT N][cntT N][sedge 2E][nd N][invcnt N][y N][z N][y2 N][z2 N]
    //   [ha 64N][habf 32N][hbbf 32N][off N+1][bsum 196]
    // histD/histC (8N each) alias ha; rankx (E) aliases habf — all dead before proj writes.
    int*   degT   = (int*)d_ws;
    int*   cntT   = degT + N_NODES;
    int2*  sedge  = (int2*)(cntT + N_NODES);
    float* nd     = (float*)(sedge + N_EDGES);
    float* invcnt = nd + N_NODES;
    float* y      = invcnt + N_NODES;
    float* z      = y + N_NODES;
    float* y2     = z + N_NODES;
    float* z2     = y2 + N_NODES;
    float* ha     = z2 + N_NODES;
    ushort* habf  = (ushort*)(ha + (size_t)N_NODES * HID);
    ushort* hbbf  = habf + (size_t)N_NODES * HID;
    int*   off    = (int*)(hbbf + (size_t)N_NODES * HID);
    int*   bsum   = off + N_NODES + 1;
    int*   histD  = (int*)ha;                  // 8N ints
    int*   histC  = histD + NXCD * N_NODES;    // 8N ints (still inside ha's 64N)
    int*   rankx  = (int*)habf;                // E ints <= 32N words

    const int* row = ei;
    const int* col = ei + N_EDGES;

    // zero the 16N replica words (histD+histC contiguous)
    hipMemsetAsync(histD, 0, (size_t)2 * NXCD * N_NODES * sizeof(int), stream);

    degree_kernel<<<N_EDGES / 256, 256, 0, stream>>>(row, col, histD, histC, rankx);
    reduce_kernel<<<SCAN_BLOCKS, 256, 0, stream>>>(histD, histC, degT, cntT);
    scan1_kernel<<<SCAN_BLOCKS, 256, 0, stream>>>(cntT, degT, off, bsum, nd, invcnt);
    scan2_kernel<<<1, 256, 0, stream>>>(bsum);
    scan3_kernel<<<SCAN_BLOCKS, 256, 0, stream>>>(off, bsum);
    scatter_kernel<<<N_EDGES / 256, 256, 0, stream>>>(row, col, rankx, histC, off, nd, sedge);
    proj_kernel<<<(N_NODES + 63) / 64, 256, 0, stream>>>(x, W1, b1, ha, habf);
    yz_kernel<<<N_NODES / 4, 256, 0, stream>>>(ha, gw, y, z);

    agg1_kernel<<<N_NODES / 4, 256, 0, stream>>>(ha, habf, sedge, off, invcnt, y, z, gb,
                                                 gw + 2 * HID, hbbf, y2, z2);
    agg2_kernel<<<N_NODES / 4, 256, 0, stream>>>(hbbf, ha, sedge, off, invcnt, y2, z2,
                                                 gb + 1, W2, b2, out);
}